// Round 2
// baseline (48.530 us; speedup 1.0000x reference)
//
#include <hip/hip_runtime.h>

// Locally-connected 2D conv, fp32.
// x:(8,32,64,64)  weights:(64,64,32,32,3,3)  bias:(32)  out:(8,32,64,64)
// out[b,o,i,j] = bias[o] + sum_{c,d4,d5} x[b,c,i+d5-1,j+d4-1] * W[i,j,o,c,d4,d5]
// (weight kernel dims spatially transposed vs patch, per 'bchwij,ijocwh->boij')
//
// One 128-thread WG per location. Thread (og=t>>3, kc=t&7) owns output
// channels o0=2og, o1=2og+1 and the interleaved K-chunk {kc+8s : s=0..8}
// (float4 units). Weight loads: 8-lane kc-groups read contiguous 128-B
// segments. x patch staged once in LDS, each ds_read_b128 feeds 2 o's.

#define NB 8
#define NC 32
#define NO 32
#define NH 64
#define NW 64
#define KK 288   // NC*3*3
#define K4 72    // KK/4

__device__ __forceinline__ float reduce8(const float a[8], int kc) {
  // Butterfly reduce-scatter over the 8 kc-lanes: lane kc ends with the
  // full K-sum for batch b == kc.
  float p8[8];
#pragma unroll
  for (int b = 0; b < 8; ++b) p8[b] = __shfl_xor(a[b], 4);
  float c4[4];
#pragma unroll
  for (int b = 0; b < 4; ++b)
    c4[b] = (kc & 4) ? (a[b + 4] + p8[b + 4]) : (a[b] + p8[b]);
  float p4[4];
#pragma unroll
  for (int b = 0; b < 4; ++b) p4[b] = __shfl_xor(c4[b], 2);
  float c2[2];
#pragma unroll
  for (int b = 0; b < 2; ++b)
    c2[b] = (kc & 2) ? (c4[b + 2] + p4[b + 2]) : (c4[b] + p4[b]);
  float p2[2];
#pragma unroll
  for (int b = 0; b < 2; ++b) p2[b] = __shfl_xor(c2[b], 1);
  return (kc & 1) ? (c2[1] + p2[1]) : (c2[0] + p2[0]);
}

__global__ __launch_bounds__(128) void lc2d_kernel(
    const float* __restrict__ x, const float* __restrict__ w,
    const float* __restrict__ bias, float* __restrict__ out) {
  const int loc = blockIdx.x;          // i*64 + j
  const int i = loc >> 6;
  const int j = loc & 63;
  const int t = threadIdx.x;

  __shared__ float xs[NB * KK];        // 9216 B

  // Stage x patch: xs[b*288 + c*9 + a*3 + bb] = x[b,c,i+bb-1,j+a-1] (zero-pad)
  // 2304 elements, 18 per thread. The (c,kw,kh)->k transpose is folded here.
#pragma unroll
  for (int r = 0; r < 18; ++r) {
    int e = t + r * 128;
    int b = e / KK;
    int k = e - b * KK;
    int c = k / 9;
    int r9 = k - c * 9;
    int a = r9 / 3;                    // kw (W axis offset)
    int bb = r9 - a * 3;               // kh (H axis offset)
    int y = i + bb - 1;
    int xc = j + a - 1;
    float v = 0.f;
    if ((unsigned)y < 64u && (unsigned)xc < 64u)
      v = x[((b * NC + c) * NH + y) * NW + xc];
    xs[e] = v;
  }
  __syncthreads();

  const int kc = t & 7;
  const int og = t >> 3;               // 0..15
  const int o0 = og * 2;
  const int o1 = o0 + 1;

  const float4* w40 = reinterpret_cast<const float4*>(w) +
                      ((size_t)loc * NO + o0) * K4 + kc;
  const float4* w41 = w40 + K4;
  const float4* xs4 = reinterpret_cast<const float4*>(xs);

  float acc0[NB], acc1[NB];
#pragma unroll
  for (int b = 0; b < NB; ++b) { acc0[b] = 0.f; acc1[b] = 0.f; }

#pragma unroll
  for (int s = 0; s < 9; ++s) {
    float4 wv0 = w40[s * 8];           // 128-B segment per 8-lane kc-group
    float4 wv1 = w41[s * 8];
#pragma unroll
    for (int b = 0; b < NB; ++b) {
      float4 xv = xs4[b * K4 + s * 8 + kc];   // start bank 4*kc: conflict-free
      acc0[b] = fmaf(wv0.x, xv.x, acc0[b]);
      acc0[b] = fmaf(wv0.y, xv.y, acc0[b]);
      acc0[b] = fmaf(wv0.z, xv.z, acc0[b]);
      acc0[b] = fmaf(wv0.w, xv.w, acc0[b]);
      acc1[b] = fmaf(wv1.x, xv.x, acc1[b]);
      acc1[b] = fmaf(wv1.y, xv.y, acc1[b]);
      acc1[b] = fmaf(wv1.z, xv.z, acc1[b]);
      acc1[b] = fmaf(wv1.w, xv.w, acc1[b]);
    }
  }

  float tot0 = reduce8(acc0, kc);
  float tot1 = reduce8(acc1, kc);

  out[((kc * NO + o0) * NH + i) * NW + j] = tot0 + bias[o0];
  out[((kc * NO + o1) * NH + i) * NW + j] = tot1 + bias[o1];
}

extern "C" void kernel_launch(void* const* d_in, const int* in_sizes, int n_in,
                              void* d_out, int out_size, void* d_ws, size_t ws_size,
                              hipStream_t stream) {
  const float* x    = (const float*)d_in[0];
  const float* w    = (const float*)d_in[1];
  const float* bias = (const float*)d_in[2];
  float* out = (float*)d_out;
  lc2d_kernel<<<dim3(NH * NW), dim3(128), 0, stream>>>(x, w, bias, out);
}